// Round 2
// baseline (161.317 us; speedup 1.0000x reference)
//
#include <hip/hip_runtime.h>

#define G_ 64
#define N_ 1024
#define DIN 128
#define DH 256
#define DOUT 10

typedef float floatx4 __attribute__((ext_vector_type(4)));
typedef short shortx8 __attribute__((ext_vector_type(8)));

__device__ __forceinline__ ushort f2bf(float f) {
  unsigned u = __builtin_bit_cast(unsigned, f);
  unsigned r = (u + 0x7FFFu + ((u >> 16) & 1u)) >> 16;   // RNE
  return (ushort)r;
}
__device__ __forceinline__ float bflo(unsigned q) {
  return __builtin_bit_cast(float, q << 16);
}
__device__ __forceinline__ float bfhi(unsigned q) {
  return __builtin_bit_cast(float, q & 0xFFFF0000u);
}

// ---------------------------------------------------------------------------
// kA: fused W1-transpose + per-node norms + x->bf16 + per-block u-partials.
// 512 blocks x 256 threads; block bid owns nodes m0 = bid*128 .. +127.
// Also zeroes the 64 per-graph completion counters (kB runs after kA on the
// same stream, so ordering is guaranteed).
// ---------------------------------------------------------------------------
__global__ __launch_bounds__(256) void kA(
    const float* __restrict__ x, const float* __restrict__ W1,
    ushort* __restrict__ xb, ushort* __restrict__ w1t,
    float* __restrict__ u_part, float* __restrict__ norminv,
    int* __restrict__ cnt) {
  const int bid = blockIdx.x;
  const int tid = threadIdx.x;
  const int wave = tid >> 6;
  const int lane = tid & 63;
  const int m0 = bid << 7;

  __shared__ float red[4][DIN];

  if (bid == 0 && tid < G_) cnt[tid] = 0;

  // W1 [128][256] f32 -> w1t [256][128] bf16 (blocks 0..127, coalesced read)
  if (bid < DIN)
    w1t[(size_t)tid * DIN + bid] = f2bf(W1[(size_t)bid * DH + tid]);

  // norms + u-partials + bf16 conversion (32 nodes per wave)
  float a0 = 0.f, a1 = 0.f;
  for (int i = 0; i < 32; ++i) {
    const int nb = (wave << 5) + i;
    const int m = m0 + nb;
    const float2 v = ((const float2*)(x + (size_t)m * DIN))[lane];
    float ss = v.x * v.x + v.y * v.y;
    #pragma unroll
    for (int off = 32; off; off >>= 1) ss += __shfl_xor(ss, off, 64);
    const float ninv = rsqrtf(ss + 1e-24f);
    if (lane == 0) norminv[m] = ninv;
    ((unsigned*)xb)[(size_t)m * (DIN / 2) + lane] =
        (unsigned)f2bf(v.x) | ((unsigned)f2bf(v.y) << 16);
    a0 = fmaf(v.x, ninv, a0);
    a1 = fmaf(v.y, ninv, a1);
  }
  red[wave][2 * lane] = a0;
  red[wave][2 * lane + 1] = a1;
  __syncthreads();
  if (tid < DIN)
    u_part[bid * DIN + tid] =
        red[0][tid] + red[1][tid] + red[2][tid] + red[3][tid];
}

// ---------------------------------------------------------------------------
// kB: fused s-weights + bf16 MFMA + per-block hw-partials + last-block head.
// 512 blocks x 256 threads; block bid owns graph g = bid>>3, nodes
// m0 = bid*128 .. +127. The last of each graph's 8 blocks (device-scope
// counter + fences) sums the 8 hw_part slices and runs fc2 + pool +
// log-softmax for that graph.
// ---------------------------------------------------------------------------
__global__ __launch_bounds__(256) void kB(
    const ushort* __restrict__ xb, const ushort* __restrict__ w1t,
    const float* __restrict__ b1, const float* __restrict__ W2,
    const float* __restrict__ b2, const float* __restrict__ u_part,
    const float* __restrict__ norminv, float* __restrict__ hw_part,
    int* __restrict__ cnt, float* __restrict__ out) {
  const int bid = blockIdx.x;
  const int tid = threadIdx.x;
  const int wave = tid >> 6;
  const int lane = tid & 63;
  const int g = bid >> 3;
  const int m0 = bid << 7;

  __shared__ float u_lds[DIN];
  __shared__ float s_lds[128];
  __shared__ float hv[DH];
  __shared__ float partial[40];
  __shared__ float pv[DOUT];
  __shared__ int lastflag;

  // u for graph g = sum of its 8 block partials
  if (tid < DIN) {
    float s = 0.f;
    #pragma unroll
    for (int i = 0; i < 8; ++i) s += u_part[((g << 3) + i) * DIN + tid];
    u_lds[tid] = s;
  }
  __syncthreads();

  // s[m] = ninv[m]*(u . x[m]) - 1  (2 threads/node)
  {
    const int nd = tid >> 1;
    const int half = tid & 1;
    const uint4* xr = (const uint4*)(xb + ((size_t)m0 + nd) * DIN + half * 64);
    float p = 0.f;
    #pragma unroll
    for (int j = 0; j < 8; ++j) {
      const uint4 q = xr[j];
      const float* ub = &u_lds[half * 64 + j * 8];
      p = fmaf(bflo(q.x), ub[0], p); p = fmaf(bfhi(q.x), ub[1], p);
      p = fmaf(bflo(q.y), ub[2], p); p = fmaf(bfhi(q.y), ub[3], p);
      p = fmaf(bflo(q.z), ub[4], p); p = fmaf(bfhi(q.z), ub[5], p);
      p = fmaf(bflo(q.w), ub[6], p); p = fmaf(bfhi(q.w), ub[7], p);
    }
    p += __shfl_xor(p, 1, 64);
    if (!half) s_lds[nd] = p * norminv[m0 + nd] - 1.0f;
  }
  __syncthreads();

  // MFMA: hw_part[bid][d] = sum_m s[m]*relu(x[m]@W1+b1)[d]
  const int quad = lane >> 4;
  const int l16 = lane & 15;

  shortx8 bfr[4][4];   // wave's 64-d slice of W1t; B[k][n]: n=l16, k=quad*8+j
  #pragma unroll
  for (int dt = 0; dt < 4; ++dt) {
    const int d = (wave << 6) + (dt << 4) + l16;
    #pragma unroll
    for (int kt = 0; kt < 4; ++kt)
      bfr[dt][kt] =
          *(const shortx8*)(w1t + (size_t)d * DIN + (kt << 5) + (quad << 3));
  }
  float b1v[4];
  #pragma unroll
  for (int dt = 0; dt < 4; ++dt) b1v[dt] = b1[(wave << 6) + (dt << 4) + l16];

  float wsum[4] = {0.f, 0.f, 0.f, 0.f};
  for (int mt = 0; mt < 8; ++mt) {
    const ushort* ar = xb + ((size_t)m0 + (mt << 4) + l16) * DIN;
    shortx8 af[4];
    #pragma unroll
    for (int kt = 0; kt < 4; ++kt)
      af[kt] = *(const shortx8*)(ar + (kt << 5) + (quad << 3));

    floatx4 acc[4] = {{0.f, 0.f, 0.f, 0.f}, {0.f, 0.f, 0.f, 0.f},
                      {0.f, 0.f, 0.f, 0.f}, {0.f, 0.f, 0.f, 0.f}};
    #pragma unroll
    for (int kt = 0; kt < 4; ++kt)
      #pragma unroll
      for (int dt = 0; dt < 4; ++dt)
        acc[dt] = __builtin_amdgcn_mfma_f32_16x16x32_bf16(af[kt], bfr[dt][kt],
                                                          acc[dt], 0, 0, 0);
    #pragma unroll
    for (int dt = 0; dt < 4; ++dt) {
      float bs = 0.f;
      #pragma unroll
      for (int r = 0; r < 4; ++r) {
        const float h = fmaxf(acc[dt][r] + b1v[dt], 0.f);
        bs = fmaf(s_lds[(mt << 4) + (quad << 2) + r], h, bs);
      }
      wsum[dt] += bs;
    }
  }
  #pragma unroll
  for (int dt = 0; dt < 4; ++dt) {
    float w = wsum[dt];
    w += __shfl_xor(w, 16, 64);
    w += __shfl_xor(w, 32, 64);
    if (quad == 0)
      hw_part[bid * DH + (wave << 6) + (dt << 4) + l16] = w;
  }

  // last-block-done: device-scope release, counter, acquire
  __syncthreads();
  __threadfence();
  if (tid == 0) lastflag = (atomicAdd(&cnt[g], 1) == 7);
  __syncthreads();
  if (!lastflag) return;
  __threadfence();   // acquire: invalidate stale cache lines before reads

  // head for graph g: hw sum, fc2, mean-pool, log-softmax
  float h = 0.f;
  #pragma unroll
  for (int i = 0; i < 8; ++i) h += hw_part[((g << 3) + i) * DH + tid];
  hv[tid] = h;
  __syncthreads();
  if (tid < 40) {
    const int c = tid % 10, q = tid / 10;
    float a = 0.f;
    #pragma unroll
    for (int k = 0; k < 64; ++k)
      a = fmaf(hv[q * 64 + k], W2[(q * 64 + k) * DOUT + c], a);
    partial[tid] = a;
  }
  __syncthreads();
  if (tid < DOUT) {
    pv[tid] = (partial[tid] + partial[tid + 10] + partial[tid + 20] +
               partial[tid + 30]) * (1.0f / N_) + b2[tid];
  }
  __syncthreads();
  if (tid < DOUT) {
    float mx = pv[0];
    #pragma unroll
    for (int c = 1; c < DOUT; ++c) mx = fmaxf(mx, pv[c]);
    float se = 0.f;
    #pragma unroll
    for (int c = 0; c < DOUT; ++c) se += expf(pv[c] - mx);
    out[g * DOUT + tid] = pv[tid] - (mx + logf(se));
  }
}

extern "C" void kernel_launch(void* const* d_in, const int* in_sizes, int n_in,
                              void* d_out, int out_size, void* d_ws, size_t ws_size,
                              hipStream_t stream) {
  const float* x  = (const float*)d_in[0];
  // d_in[1] = batch (sorted, equal-sized) -> unused
  const float* W1 = (const float*)d_in[2];
  const float* b1 = (const float*)d_in[3];
  const float* W2 = (const float*)d_in[4];
  const float* b2 = (const float*)d_in[5];
  float* out = (float*)d_out;

  // ws layout: xb [65536][128] bf16 (16 MB) | w1t [256][128] bf16 (64 KB)
  //   | u_part [512][128] f32 | hw_part [512][256] f32 | norminv [65536] f32
  //   | cnt [64] i32
  ushort* xb  = (ushort*)d_ws;
  ushort* w1t = xb + (size_t)G_ * N_ * DIN;
  float* u_part  = (float*)(w1t + (size_t)DH * DIN);
  float* hw_part = u_part + (size_t)512 * DIN;
  float* norminv = hw_part + (size_t)512 * DH;
  int* cnt = (int*)(norminv + (size_t)G_ * N_);

  kA<<<512, 256, 0, stream>>>(x, W1, xb, w1t, u_part, norminv, cnt);
  kB<<<512, 256, 0, stream>>>(xb, w1t, b1, W2, b2, u_part, norminv, hw_part,
                              cnt, out);
}

// Round 3
// 117.010 us; speedup vs baseline: 1.3787x; 1.3787x over previous
//
#include <hip/hip_runtime.h>

#define G_ 64
#define N_ 1024
#define DIN 128
#define DH 256
#define DOUT 10

typedef float floatx4 __attribute__((ext_vector_type(4)));
typedef short shortx8 __attribute__((ext_vector_type(8)));

__device__ __forceinline__ ushort f2bf(float f) {
  unsigned u = __builtin_bit_cast(unsigned, f);
  unsigned r = (u + 0x7FFFu + ((u >> 16) & 1u)) >> 16;   // RNE
  return (ushort)r;
}
__device__ __forceinline__ float bflo(unsigned q) {
  return __builtin_bit_cast(float, q << 16);
}
__device__ __forceinline__ float bfhi(unsigned q) {
  return __builtin_bit_cast(float, q & 0xFFFF0000u);
}

// ---------------------------------------------------------------------------
// k1: fused W1-transpose + per-node norms + x->bf16 + per-block u-partials.
// 512 blocks x 256 threads; block bid owns nodes m0 = bid*128 .. +127.
// No atomics: each block writes its own u_part row; k2 sums the 8 rows.
// ---------------------------------------------------------------------------
__global__ __launch_bounds__(256) void k1(
    const float* __restrict__ x, const float* __restrict__ W1,
    ushort* __restrict__ xb, ushort* __restrict__ w1t,
    float* __restrict__ u_part, float* __restrict__ norminv) {
  const int bid = blockIdx.x;
  const int tid = threadIdx.x;
  const int wave = tid >> 6;
  const int lane = tid & 63;
  const int m0 = bid << 7;

  __shared__ float red[4][DIN];

  // W1 [128][256] f32 -> w1t [256][128] bf16 (blocks 0..127, coalesced read)
  if (bid < DIN)
    w1t[(size_t)tid * DIN + bid] = f2bf(W1[(size_t)bid * DH + tid]);

  // norms + u-partials + bf16 conversion (32 nodes per wave)
  float a0 = 0.f, a1 = 0.f;
  for (int i = 0; i < 32; ++i) {
    const int nb = (wave << 5) + i;
    const int m = m0 + nb;
    const float2 v = ((const float2*)(x + (size_t)m * DIN))[lane];
    float ss = v.x * v.x + v.y * v.y;
    #pragma unroll
    for (int off = 32; off; off >>= 1) ss += __shfl_xor(ss, off, 64);
    const float ninv = rsqrtf(ss + 1e-24f);
    if (lane == 0) norminv[m] = ninv;
    ((unsigned*)xb)[(size_t)m * (DIN / 2) + lane] =
        (unsigned)f2bf(v.x) | ((unsigned)f2bf(v.y) << 16);
    a0 = fmaf(v.x, ninv, a0);
    a1 = fmaf(v.y, ninv, a1);
  }
  red[wave][2 * lane] = a0;
  red[wave][2 * lane + 1] = a1;
  __syncthreads();
  if (tid < DIN)
    u_part[bid * DIN + tid] =
        red[0][tid] + red[1][tid] + red[2][tid] + red[3][tid];
}

// ---------------------------------------------------------------------------
// k2: s-weights + bf16 MFMA -> per-block hw-partials. Plain stores, no
// atomics/fences; the k2->k3 dispatch boundary provides coherence.
// 512 blocks x 256 threads; block bid owns graph g = bid>>3, 128 nodes.
// ---------------------------------------------------------------------------
__global__ __launch_bounds__(256) void k2(
    const ushort* __restrict__ xb, const ushort* __restrict__ w1t,
    const float* __restrict__ b1, const float* __restrict__ u_part,
    const float* __restrict__ norminv, float* __restrict__ hw_part) {
  const int bid = blockIdx.x;
  const int tid = threadIdx.x;
  const int wave = tid >> 6;
  const int lane = tid & 63;
  const int g = bid >> 3;
  const int m0 = bid << 7;

  __shared__ float u_lds[DIN];
  __shared__ float s_lds[128];

  // u for graph g = sum of its 8 block partials
  if (tid < DIN) {
    float s = 0.f;
    #pragma unroll
    for (int i = 0; i < 8; ++i) s += u_part[((g << 3) + i) * DIN + tid];
    u_lds[tid] = s;
  }
  __syncthreads();

  // s[m] = ninv[m]*(u . x[m]) - 1  (2 threads/node)
  {
    const int nd = tid >> 1;
    const int half = tid & 1;
    const uint4* xr = (const uint4*)(xb + ((size_t)m0 + nd) * DIN + half * 64);
    float p = 0.f;
    #pragma unroll
    for (int j = 0; j < 8; ++j) {
      const uint4 q = xr[j];
      const float* ub = &u_lds[half * 64 + j * 8];
      p = fmaf(bflo(q.x), ub[0], p); p = fmaf(bfhi(q.x), ub[1], p);
      p = fmaf(bflo(q.y), ub[2], p); p = fmaf(bfhi(q.y), ub[3], p);
      p = fmaf(bflo(q.z), ub[4], p); p = fmaf(bfhi(q.z), ub[5], p);
      p = fmaf(bflo(q.w), ub[6], p); p = fmaf(bfhi(q.w), ub[7], p);
    }
    p += __shfl_xor(p, 1, 64);
    if (!half) s_lds[nd] = p * norminv[m0 + nd] - 1.0f;
  }
  __syncthreads();

  // MFMA: hw_part[bid][d] = sum_m s[m]*relu(x[m]@W1+b1)[d]
  const int quad = lane >> 4;
  const int l16 = lane & 15;

  shortx8 bfr[4][4];   // wave's 64-d slice of W1t; B[k][n]: n=l16, k=quad*8+j
  #pragma unroll
  for (int dt = 0; dt < 4; ++dt) {
    const int d = (wave << 6) + (dt << 4) + l16;
    #pragma unroll
    for (int kt = 0; kt < 4; ++kt)
      bfr[dt][kt] =
          *(const shortx8*)(w1t + (size_t)d * DIN + (kt << 5) + (quad << 3));
  }
  float b1v[4];
  #pragma unroll
  for (int dt = 0; dt < 4; ++dt) b1v[dt] = b1[(wave << 6) + (dt << 4) + l16];

  float wsum[4] = {0.f, 0.f, 0.f, 0.f};
  for (int mt = 0; mt < 8; ++mt) {
    const ushort* ar = xb + ((size_t)m0 + (mt << 4) + l16) * DIN;
    shortx8 af[4];
    #pragma unroll
    for (int kt = 0; kt < 4; ++kt)
      af[kt] = *(const shortx8*)(ar + (kt << 5) + (quad << 3));

    floatx4 acc[4] = {{0.f, 0.f, 0.f, 0.f}, {0.f, 0.f, 0.f, 0.f},
                      {0.f, 0.f, 0.f, 0.f}, {0.f, 0.f, 0.f, 0.f}};
    #pragma unroll
    for (int kt = 0; kt < 4; ++kt)
      #pragma unroll
      for (int dt = 0; dt < 4; ++dt)
        acc[dt] = __builtin_amdgcn_mfma_f32_16x16x32_bf16(af[kt], bfr[dt][kt],
                                                          acc[dt], 0, 0, 0);
    #pragma unroll
    for (int dt = 0; dt < 4; ++dt) {
      float bs = 0.f;
      #pragma unroll
      for (int r = 0; r < 4; ++r) {
        const float h = fmaxf(acc[dt][r] + b1v[dt], 0.f);
        bs = fmaf(s_lds[(mt << 4) + (quad << 2) + r], h, bs);
      }
      wsum[dt] += bs;
    }
  }
  #pragma unroll
  for (int dt = 0; dt < 4; ++dt) {
    float w = wsum[dt];
    w += __shfl_xor(w, 16, 64);
    w += __shfl_xor(w, 32, 64);
    if (quad == 0)
      hw_part[bid * DH + (wave << 6) + (dt << 4) + l16] = w;
  }
}

// ---------------------------------------------------------------------------
// k3: head. One 256-thread block per graph: sum 8 hw_part slices, fc2,
// mean-pool, log-softmax.
// ---------------------------------------------------------------------------
__global__ __launch_bounds__(256) void k3(
    const float* __restrict__ hw_part, const float* __restrict__ W2,
    const float* __restrict__ b2, float* __restrict__ out) {
  const int g = blockIdx.x;
  const int tid = threadIdx.x;
  __shared__ float hv[DH];
  __shared__ float partial[40];
  __shared__ float pv[DOUT];

  float h = 0.f;
  #pragma unroll
  for (int i = 0; i < 8; ++i) h += hw_part[((g << 3) + i) * DH + tid];
  hv[tid] = h;
  __syncthreads();
  if (tid < 40) {
    const int c = tid % 10, q = tid / 10;
    float a = 0.f;
    #pragma unroll
    for (int k = 0; k < 64; ++k)
      a = fmaf(hv[q * 64 + k], W2[(q * 64 + k) * DOUT + c], a);
    partial[tid] = a;
  }
  __syncthreads();
  if (tid < DOUT) {
    pv[tid] = (partial[tid] + partial[tid + 10] + partial[tid + 20] +
               partial[tid + 30]) * (1.0f / N_) + b2[tid];
  }
  __syncthreads();
  if (tid < DOUT) {
    float mx = pv[0];
    #pragma unroll
    for (int c = 1; c < DOUT; ++c) mx = fmaxf(mx, pv[c]);
    float se = 0.f;
    #pragma unroll
    for (int c = 0; c < DOUT; ++c) se += expf(pv[c] - mx);
    out[g * DOUT + tid] = pv[tid] - (mx + logf(se));
  }
}

extern "C" void kernel_launch(void* const* d_in, const int* in_sizes, int n_in,
                              void* d_out, int out_size, void* d_ws, size_t ws_size,
                              hipStream_t stream) {
  const float* x  = (const float*)d_in[0];
  // d_in[1] = batch (sorted, equal-sized) -> unused
  const float* W1 = (const float*)d_in[2];
  const float* b1 = (const float*)d_in[3];
  const float* W2 = (const float*)d_in[4];
  const float* b2 = (const float*)d_in[5];
  float* out = (float*)d_out;

  // ws layout: xb [65536][128] bf16 (16 MB) | w1t [256][128] bf16 (64 KB)
  //   | u_part [512][128] f32 | hw_part [512][256] f32 | norminv [65536] f32
  ushort* xb  = (ushort*)d_ws;
  ushort* w1t = xb + (size_t)G_ * N_ * DIN;
  float* u_part  = (float*)(w1t + (size_t)DH * DIN);
  float* hw_part = u_part + (size_t)512 * DIN;
  float* norminv = hw_part + (size_t)512 * DH;

  k1<<<512, 256, 0, stream>>>(x, W1, xb, w1t, u_part, norminv);
  k2<<<512, 256, 0, stream>>>(xb, w1t, b1, u_part, norminv, hw_part);
  k3<<<G_, 256, 0, stream>>>(hw_part, W2, b2, out);
}

// Round 4
// 105.857 us; speedup vs baseline: 1.5239x; 1.1054x over previous
//
#include <hip/hip_runtime.h>

#define G_ 64
#define N_ 1024
#define DIN 128
#define DH 256
#define DOUT 10

typedef float floatx4 __attribute__((ext_vector_type(4)));
typedef short shortx8 __attribute__((ext_vector_type(8)));

__device__ __forceinline__ ushort f2bf(float f) {
  unsigned u = __builtin_bit_cast(unsigned, f);
  unsigned r = (u + 0x7FFFu + ((u >> 16) & 1u)) >> 16;   // RNE
  return (ushort)r;
}
__device__ __forceinline__ float bflo(unsigned q) {
  return __builtin_bit_cast(float, q << 16);
}
__device__ __forceinline__ float bfhi(unsigned q) {
  return __builtin_bit_cast(float, q & 0xFFFF0000u);
}

// ---------------------------------------------------------------------------
// k1: W1-transpose + per-node norms + x->bf16 + per-block u-partials.
// 1024 blocks x 256 threads (4 waves/SIMD for latency hiding); block owns
// 64 nodes. Each wave processes 2 rows/iter via float4 (16B/lane): the norm
// reduce is 5 shfl_xor per 2 rows (vs 6/row before). u accumulated per-lane
// in registers, one LDS reduce at the end. No atomics.
// ---------------------------------------------------------------------------
__global__ __launch_bounds__(256) void k1(
    const float* __restrict__ x, const float* __restrict__ W1,
    ushort* __restrict__ xb, ushort* __restrict__ w1t,
    float* __restrict__ u_part, float* __restrict__ norminv) {
  const int bid = blockIdx.x;
  const int tid = threadIdx.x;
  const int wave = tid >> 6;
  const int lane = tid & 63;
  const int half = lane >> 5;        // which of the 2 rows this iter
  const int l32 = lane & 31;         // 32 lanes x float4 = 128 cols
  const int m0 = bid << 6;           // 64 nodes per block

  __shared__ float red[8][DIN];      // 4 KB

  // W1 [128][256] f32 -> w1t [256][128] bf16 (blocks 0..127)
  if (bid < DIN)
    w1t[(size_t)tid * DIN + bid] = f2bf(W1[(size_t)bid * DH + tid]);

  float a0 = 0.f, a1 = 0.f, a2 = 0.f, a3 = 0.f;
  #pragma unroll
  for (int it = 0; it < 8; ++it) {
    const int m = m0 + (wave << 4) + (it << 1) + half;
    const float4 v = ((const float4*)(x + (size_t)m * DIN))[l32];
    float ss = v.x * v.x + v.y * v.y + v.z * v.z + v.w * v.w;
    #pragma unroll
    for (int off = 16; off; off >>= 1) ss += __shfl_xor(ss, off, 64);
    const float ninv = rsqrtf(ss + 1e-24f);
    if (l32 == 0) norminv[m] = ninv;
    const unsigned lo = (unsigned)f2bf(v.x) | ((unsigned)f2bf(v.y) << 16);
    const unsigned hi = (unsigned)f2bf(v.z) | ((unsigned)f2bf(v.w) << 16);
    uint2 pk; pk.x = lo; pk.y = hi;
    ((uint2*)xb)[(size_t)m * 32 + l32] = pk;   // row = 32 uint2, coalesced
    a0 = fmaf(v.x, ninv, a0);
    a1 = fmaf(v.y, ninv, a1);
    a2 = fmaf(v.z, ninv, a2);
    a3 = fmaf(v.w, ninv, a3);
  }
  float4 av; av.x = a0; av.y = a1; av.z = a2; av.w = a3;
  ((float4*)red[(wave << 1) + half])[l32] = av;
  __syncthreads();
  if (tid < DIN) {
    float s = 0.f;
    #pragma unroll
    for (int i = 0; i < 8; ++i) s += red[i][tid];
    u_part[bid * DIN + tid] = s;
  }
}

// ---------------------------------------------------------------------------
// k2: fused s + MFMA -> per-block hw-partials. The s-weights are computed
// FROM the A-fragments inside the main loop (no separate pass over xb):
// each lane preloads its 32 u-coefficients (mt-invariant columns), unpack-
// dots the bf16 fragment on the VALU pipe (co-issues under MFMA), reduces
// across quads with shfl_xor(16/32), and broadcasts s[row] to the epilogue
// with 4 per-lane shuffles. Plain stores; k2->k3 boundary is the fence.
// 512 blocks x 256 threads; block owns graph g = bid>>3, 128 nodes.
// ---------------------------------------------------------------------------
__global__ __launch_bounds__(256) void k2(
    const ushort* __restrict__ xb, const ushort* __restrict__ w1t,
    const float* __restrict__ b1, const float* __restrict__ u_part,
    const float* __restrict__ norminv, float* __restrict__ hw_part) {
  const int bid = blockIdx.x;
  const int tid = threadIdx.x;
  const int wave = tid >> 6;
  const int lane = tid & 63;
  const int g = bid >> 3;
  const int m0 = bid << 7;
  const int quad = lane >> 4;
  const int l16 = lane & 15;

  __shared__ float u_lds[DIN];
  __shared__ float ninv_lds[128];

  // u for graph g = sum of its 16 block partials; ninv for block's 128 rows
  if (tid < DIN) {
    float s = 0.f;
    #pragma unroll
    for (int i = 0; i < 16; ++i) s += u_part[((g << 4) + i) * DIN + tid];
    u_lds[tid] = s;
  } else {
    ninv_lds[tid - 128] = norminv[m0 + tid - 128];
  }
  __syncthreads();

  // per-lane u slice: cols kt*32 + quad*8 + j  (fixed across all m-tiles)
  float uu[4][8];
  #pragma unroll
  for (int kt = 0; kt < 4; ++kt)
    #pragma unroll
    for (int j = 0; j < 8; ++j) uu[kt][j] = u_lds[(kt << 5) + (quad << 3) + j];

  // B fragments: wave's 64-d slice of W1t; B[k][n]: n=l16, k=quad*8+j
  shortx8 bfr[4][4];
  #pragma unroll
  for (int dt = 0; dt < 4; ++dt) {
    const int d = (wave << 6) + (dt << 4) + l16;
    #pragma unroll
    for (int kt = 0; kt < 4; ++kt)
      bfr[dt][kt] =
          *(const shortx8*)(w1t + (size_t)d * DIN + (kt << 5) + (quad << 3));
  }
  float b1v[4];
  #pragma unroll
  for (int dt = 0; dt < 4; ++dt) b1v[dt] = b1[(wave << 6) + (dt << 4) + l16];

  float wsum[4] = {0.f, 0.f, 0.f, 0.f};
  for (int mt = 0; mt < 8; ++mt) {
    // A frags: A[m][k]: m = mt*16 + l16, k = quad*8+j (+kt*32), 16B/lane
    const ushort* ar = xb + ((size_t)m0 + (mt << 4) + l16) * DIN;
    shortx8 af[4];
    #pragma unroll
    for (int kt = 0; kt < 4; ++kt)
      af[kt] = *(const shortx8*)(ar + (kt << 5) + (quad << 3));

    floatx4 acc[4] = {{0.f, 0.f, 0.f, 0.f}, {0.f, 0.f, 0.f, 0.f},
                      {0.f, 0.f, 0.f, 0.f}, {0.f, 0.f, 0.f, 0.f}};
    #pragma unroll
    for (int kt = 0; kt < 4; ++kt)
      #pragma unroll
      for (int dt = 0; dt < 4; ++dt)
        acc[dt] = __builtin_amdgcn_mfma_f32_16x16x32_bf16(af[kt], bfr[dt][kt],
                                                          acc[dt], 0, 0, 0);

    // s for row (mt*16 + l16): unpack-dot af with uu, reduce across quads
    float p = 0.f;
    #pragma unroll
    for (int kt = 0; kt < 4; ++kt) {
      const uint4 q = __builtin_bit_cast(uint4, af[kt]);
      const float* ub = uu[kt];
      p = fmaf(bflo(q.x), ub[0], p); p = fmaf(bfhi(q.x), ub[1], p);
      p = fmaf(bflo(q.y), ub[2], p); p = fmaf(bfhi(q.y), ub[3], p);
      p = fmaf(bflo(q.z), ub[4], p); p = fmaf(bfhi(q.z), ub[5], p);
      p = fmaf(bflo(q.w), ub[6], p); p = fmaf(bfhi(q.w), ub[7], p);
    }
    p += __shfl_xor(p, 16, 64);
    p += __shfl_xor(p, 32, 64);
    const float s_l = p * ninv_lds[(mt << 4) + l16] - 1.0f;

    // epilogue needs s of tile-rows quad*4+r: fetch from same-quad lane
    float sv[4];
    #pragma unroll
    for (int r = 0; r < 4; ++r)
      sv[r] = __shfl(s_l, (lane & 48) | ((quad << 2) + r), 64);

    #pragma unroll
    for (int dt = 0; dt < 4; ++dt) {
      float bs = 0.f;
      #pragma unroll
      for (int r = 0; r < 4; ++r) {
        const float h = fmaxf(acc[dt][r] + b1v[dt], 0.f);
        bs = fmaf(sv[r], h, bs);
      }
      wsum[dt] += bs;
    }
  }
  #pragma unroll
  for (int dt = 0; dt < 4; ++dt) {
    float w = wsum[dt];
    w += __shfl_xor(w, 16, 64);
    w += __shfl_xor(w, 32, 64);
    if (quad == 0)
      hw_part[bid * DH + (wave << 6) + (dt << 4) + l16] = w;
  }
}

// ---------------------------------------------------------------------------
// k3: head. One 256-thread block per graph: sum 8 hw_part slices, fc2,
// mean-pool, log-softmax.
// ---------------------------------------------------------------------------
__global__ __launch_bounds__(256) void k3(
    const float* __restrict__ hw_part, const float* __restrict__ W2,
    const float* __restrict__ b2, float* __restrict__ out) {
  const int g = blockIdx.x;
  const int tid = threadIdx.x;
  __shared__ float hv[DH];
  __shared__ float partial[40];
  __shared__ float pv[DOUT];

  float h = 0.f;
  #pragma unroll
  for (int i = 0; i < 8; ++i) h += hw_part[((g << 3) + i) * DH + tid];
  hv[tid] = h;
  __syncthreads();
  if (tid < 40) {
    const int c = tid % 10, q = tid / 10;
    float a = 0.f;
    #pragma unroll
    for (int k = 0; k < 64; ++k)
      a = fmaf(hv[q * 64 + k], W2[(q * 64 + k) * DOUT + c], a);
    partial[tid] = a;
  }
  __syncthreads();
  if (tid < DOUT) {
    pv[tid] = (partial[tid] + partial[tid + 10] + partial[tid + 20] +
               partial[tid + 30]) * (1.0f / N_) + b2[tid];
  }
  __syncthreads();
  if (tid < DOUT) {
    float mx = pv[0];
    #pragma unroll
    for (int c = 1; c < DOUT; ++c) mx = fmaxf(mx, pv[c]);
    float se = 0.f;
    #pragma unroll
    for (int c = 0; c < DOUT; ++c) se += expf(pv[c] - mx);
    out[g * DOUT + tid] = pv[tid] - (mx + logf(se));
  }
}

extern "C" void kernel_launch(void* const* d_in, const int* in_sizes, int n_in,
                              void* d_out, int out_size, void* d_ws, size_t ws_size,
                              hipStream_t stream) {
  const float* x  = (const float*)d_in[0];
  // d_in[1] = batch (sorted, equal-sized) -> unused
  const float* W1 = (const float*)d_in[2];
  const float* b1 = (const float*)d_in[3];
  const float* W2 = (const float*)d_in[4];
  const float* b2 = (const float*)d_in[5];
  float* out = (float*)d_out;

  // ws layout: xb [65536][128] bf16 (16 MB) | w1t [256][128] bf16 (64 KB)
  //   | u_part [1024][128] f32 | hw_part [512][256] f32 | norminv [65536] f32
  ushort* xb  = (ushort*)d_ws;
  ushort* w1t = xb + (size_t)G_ * N_ * DIN;
  float* u_part  = (float*)(w1t + (size_t)DH * DIN);
  float* hw_part = u_part + (size_t)1024 * DIN;
  float* norminv = hw_part + (size_t)512 * DH;

  k1<<<1024, 256, 0, stream>>>(x, W1, xb, w1t, u_part, norminv);
  k2<<<512, 256, 0, stream>>>(xb, w1t, b1, u_part, norminv, hw_part);
  k3<<<G_, 256, 0, stream>>>(hw_part, W2, b2, out);
}

// Round 5
// 104.617 us; speedup vs baseline: 1.5420x; 1.0119x over previous
//
#include <hip/hip_runtime.h>

#define G_ 64
#define N_ 1024
#define DIN 128
#define DH 256
#define DOUT 10

typedef float floatx4 __attribute__((ext_vector_type(4)));
typedef short shortx8 __attribute__((ext_vector_type(8)));

__device__ __forceinline__ ushort f2bf(float f) {
  unsigned u = __builtin_bit_cast(unsigned, f);
  unsigned r = (u + 0x7FFFu + ((u >> 16) & 1u)) >> 16;   // RNE
  return (ushort)r;
}

// packed f32x2 -> bf16x2, RNE (same rounding as f2bf). Non-volatile so the
// scheduler may reorder it freely.
__device__ __forceinline__ unsigned cvtpk(float a, float b) {
  unsigned r;
  asm("v_cvt_pk_bf16_f32 %0, %1, %2" : "=v"(r) : "v"(a), "v"(b));
  return r;
}

// ---------------------------------------------------------------------------
// k1: W1-transpose + per-node norms + per-block u-partials. No xb store:
// k2 re-reads x (L3-hot after this kernel). 1024 blocks x 256 threads;
// block owns 64 nodes; wave does 2 rows/iter via float4 (16B/lane), norm
// reduce = 5 shfl_xor per 2 rows; u kept per-lane, one LDS reduce at end.
// ---------------------------------------------------------------------------
__global__ __launch_bounds__(256) void k1(
    const float* __restrict__ x, const float* __restrict__ W1,
    ushort* __restrict__ w1t, float* __restrict__ u_part,
    float* __restrict__ norminv) {
  const int bid = blockIdx.x;
  const int tid = threadIdx.x;
  const int wave = tid >> 6;
  const int lane = tid & 63;
  const int half = lane >> 5;
  const int l32 = lane & 31;
  const int m0 = bid << 6;

  __shared__ float red[8][DIN];

  // W1 [128][256] f32 -> w1t [256][128] bf16 (blocks 0..127)
  if (bid < DIN)
    w1t[(size_t)tid * DIN + bid] = f2bf(W1[(size_t)bid * DH + tid]);

  float a0 = 0.f, a1 = 0.f, a2 = 0.f, a3 = 0.f;
  #pragma unroll
  for (int it = 0; it < 8; ++it) {
    const int m = m0 + (wave << 4) + (it << 1) + half;
    const float4 v = ((const float4*)(x + (size_t)m * DIN))[l32];
    float ss = v.x * v.x + v.y * v.y + v.z * v.z + v.w * v.w;
    #pragma unroll
    for (int off = 16; off; off >>= 1) ss += __shfl_xor(ss, off, 64);
    const float ninv = rsqrtf(ss + 1e-24f);
    if (l32 == 0) norminv[m] = ninv;
    a0 = fmaf(v.x, ninv, a0);
    a1 = fmaf(v.y, ninv, a1);
    a2 = fmaf(v.z, ninv, a2);
    a3 = fmaf(v.w, ninv, a3);
  }
  float4 av; av.x = a0; av.y = a1; av.z = a2; av.w = a3;
  ((float4*)red[(wave << 1) + half])[l32] = av;
  __syncthreads();
  if (tid < DIN) {
    float s = 0.f;
    #pragma unroll
    for (int i = 0; i < 8; ++i) s += red[i][tid];
    u_part[bid * DIN + tid] = s;
  }
}

// ---------------------------------------------------------------------------
// k2: fused s + MFMA -> per-block hw-partials, reading x DIRECTLY in fp32
// (L3-hot from k1; no bf16 intermediate in memory). Per m-tile each lane
// loads its 8-float row slices, fp32-dots them with the preloaded u slice
// (s-weight, on the VALU pipe under MFMA), and cvt_pk-packs them into the
// bf16 A-fragments. Plain stores; the k2->k3 boundary is the fence.
// 512 blocks x 256 threads; block owns graph g = bid>>3, 128 nodes.
// ---------------------------------------------------------------------------
__global__ __launch_bounds__(256) void k2(
    const float* __restrict__ x, const ushort* __restrict__ w1t,
    const float* __restrict__ b1, const float* __restrict__ u_part,
    const float* __restrict__ norminv, float* __restrict__ hw_part) {
  const int bid = blockIdx.x;
  const int tid = threadIdx.x;
  const int wave = tid >> 6;
  const int lane = tid & 63;
  const int g = bid >> 3;
  const int m0 = bid << 7;
  const int quad = lane >> 4;
  const int l16 = lane & 15;

  __shared__ float u_lds[DIN];
  __shared__ float ninv_lds[128];

  // u for graph g = sum of its 16 block partials; ninv for block's 128 rows
  if (tid < DIN) {
    float s = 0.f;
    #pragma unroll
    for (int i = 0; i < 16; ++i) s += u_part[((g << 4) + i) * DIN + tid];
    u_lds[tid] = s;
  } else {
    ninv_lds[tid - 128] = norminv[m0 + tid - 128];
  }
  __syncthreads();

  // per-lane u slice: cols kt*32 + quad*8 + j  (fixed across all m-tiles)
  float uu[4][8];
  #pragma unroll
  for (int kt = 0; kt < 4; ++kt)
    #pragma unroll
    for (int j = 0; j < 8; ++j) uu[kt][j] = u_lds[(kt << 5) + (quad << 3) + j];

  // B fragments: wave's 64-d slice of W1t; B[k][n]: n=l16, k=quad*8+j
  shortx8 bfr[4][4];
  #pragma unroll
  for (int dt = 0; dt < 4; ++dt) {
    const int d = (wave << 6) + (dt << 4) + l16;
    #pragma unroll
    for (int kt = 0; kt < 4; ++kt)
      bfr[dt][kt] =
          *(const shortx8*)(w1t + (size_t)d * DIN + (kt << 5) + (quad << 3));
  }
  float b1v[4];
  #pragma unroll
  for (int dt = 0; dt < 4; ++dt) b1v[dt] = b1[(wave << 6) + (dt << 4) + l16];

  float wsum[4] = {0.f, 0.f, 0.f, 0.f};
  for (int mt = 0; mt < 8; ++mt) {
    // lane's row: m = mt*16 + l16; slices kt*32 + quad*8 .. +8 (32B, 2xfloat4)
    const float4* xr =
        (const float4*)(x + ((size_t)m0 + (mt << 4) + l16) * DIN);
    shortx8 af[4];
    float p = 0.f;
    #pragma unroll
    for (int kt = 0; kt < 4; ++kt) {
      const float4 fa = xr[(kt << 3) + (quad << 1)];
      const float4 fb = xr[(kt << 3) + (quad << 1) + 1];
      const float* ub = uu[kt];
      p = fmaf(fa.x, ub[0], p); p = fmaf(fa.y, ub[1], p);
      p = fmaf(fa.z, ub[2], p); p = fmaf(fa.w, ub[3], p);
      p = fmaf(fb.x, ub[4], p); p = fmaf(fb.y, ub[5], p);
      p = fmaf(fb.z, ub[6], p); p = fmaf(fb.w, ub[7], p);
      uint4 pk;
      pk.x = cvtpk(fa.x, fa.y);
      pk.y = cvtpk(fa.z, fa.w);
      pk.z = cvtpk(fb.x, fb.y);
      pk.w = cvtpk(fb.z, fb.w);
      af[kt] = __builtin_bit_cast(shortx8, pk);
    }

    floatx4 acc[4] = {{0.f, 0.f, 0.f, 0.f}, {0.f, 0.f, 0.f, 0.f},
                      {0.f, 0.f, 0.f, 0.f}, {0.f, 0.f, 0.f, 0.f}};
    #pragma unroll
    for (int kt = 0; kt < 4; ++kt)
      #pragma unroll
      for (int dt = 0; dt < 4; ++dt)
        acc[dt] = __builtin_amdgcn_mfma_f32_16x16x32_bf16(af[kt], bfr[dt][kt],
                                                          acc[dt], 0, 0, 0);

    // s for row (mt*16 + l16): reduce fp32 dot across quads
    p += __shfl_xor(p, 16, 64);
    p += __shfl_xor(p, 32, 64);
    const float s_l = p * ninv_lds[(mt << 4) + l16] - 1.0f;

    // epilogue needs s of tile-rows quad*4+r
    float sv[4];
    #pragma unroll
    for (int r = 0; r < 4; ++r)
      sv[r] = __shfl(s_l, (lane & 48) | ((quad << 2) + r), 64);

    #pragma unroll
    for (int dt = 0; dt < 4; ++dt) {
      float bs = 0.f;
      #pragma unroll
      for (int r = 0; r < 4; ++r) {
        const float h = fmaxf(acc[dt][r] + b1v[dt], 0.f);
        bs = fmaf(sv[r], h, bs);
      }
      wsum[dt] += bs;
    }
  }
  #pragma unroll
  for (int dt = 0; dt < 4; ++dt) {
    float w = wsum[dt];
    w += __shfl_xor(w, 16, 64);
    w += __shfl_xor(w, 32, 64);
    if (quad == 0)
      hw_part[bid * DH + (wave << 6) + (dt << 4) + l16] = w;
  }
}

// ---------------------------------------------------------------------------
// k3: head. One 256-thread block per graph: sum 8 hw_part slices, fc2,
// mean-pool, log-softmax.
// ---------------------------------------------------------------------------
__global__ __launch_bounds__(256) void k3(
    const float* __restrict__ hw_part, const float* __restrict__ W2,
    const float* __restrict__ b2, float* __restrict__ out) {
  const int g = blockIdx.x;
  const int tid = threadIdx.x;
  __shared__ float hv[DH];
  __shared__ float partial[40];
  __shared__ float pv[DOUT];

  float h = 0.f;
  #pragma unroll
  for (int i = 0; i < 8; ++i) h += hw_part[((g << 3) + i) * DH + tid];
  hv[tid] = h;
  __syncthreads();
  if (tid < 40) {
    const int c = tid % 10, q = tid / 10;
    float a = 0.f;
    #pragma unroll
    for (int k = 0; k < 64; ++k)
      a = fmaf(hv[q * 64 + k], W2[(q * 64 + k) * DOUT + c], a);
    partial[tid] = a;
  }
  __syncthreads();
  if (tid < DOUT) {
    pv[tid] = (partial[tid] + partial[tid + 10] + partial[tid + 20] +
               partial[tid + 30]) * (1.0f / N_) + b2[tid];
  }
  __syncthreads();
  if (tid < DOUT) {
    float mx = pv[0];
    #pragma unroll
    for (int c = 1; c < DOUT; ++c) mx = fmaxf(mx, pv[c]);
    float se = 0.f;
    #pragma unroll
    for (int c = 0; c < DOUT; ++c) se += expf(pv[c] - mx);
    out[g * DOUT + tid] = pv[tid] - (mx + logf(se));
  }
}

extern "C" void kernel_launch(void* const* d_in, const int* in_sizes, int n_in,
                              void* d_out, int out_size, void* d_ws, size_t ws_size,
                              hipStream_t stream) {
  const float* x  = (const float*)d_in[0];
  // d_in[1] = batch (sorted, equal-sized) -> unused
  const float* W1 = (const float*)d_in[2];
  const float* b1 = (const float*)d_in[3];
  const float* W2 = (const float*)d_in[4];
  const float* b2 = (const float*)d_in[5];
  float* out = (float*)d_out;

  // ws layout: w1t [256][128] bf16 (64 KB) | u_part [1024][128] f32 (512 KB)
  //   | hw_part [512][256] f32 (512 KB) | norminv [65536] f32 (256 KB)
  ushort* w1t = (ushort*)d_ws;
  float* u_part  = (float*)(w1t + (size_t)DH * DIN);
  float* hw_part = u_part + (size_t)1024 * DIN;
  float* norminv = hw_part + (size_t)512 * DH;

  k1<<<1024, 256, 0, stream>>>(x, W1, w1t, u_part, norminv);
  k2<<<512, 256, 0, stream>>>(x, w1t, b1, u_part, norminv, hw_part);
  k3<<<G_, 256, 0, stream>>>(hw_part, W2, b2, out);
}